// Round 4
// baseline (631.933 us; speedup 1.0000x reference)
//
#include <hip/hip_runtime.h>
#include <math.h>

namespace {
constexpr int Cn = 256;
constexpr int Kn = 19;
constexpr int HW = 256 * 256;          // 65536
constexpr int P  = 4 * HW;             // 262144 pixels
constexpr float TAUv = 0.07f;
constexpr float EPSv = 1e-12f;

// workspace layout (floats)
constexpr int K0_OFF   = 0;            // [19][256] prototype accumulators
constexpr int K0N_OFF  = 4864;         // [19][256] normalized prototypes
constexpr int SUMS_OFF = 9728;         // {loss_sum, num_pos}
constexpr int ZERO_N   = 9730;
constexpr int P1_GRID  = 1024;
constexpr int P3_GRID  = P / 512;      // 512 blocks, 4 px/thread, 128 thr
}

// Wave-uniform broadcast -> SGPR (selects become s_cselect, FMA takes scalar).
__device__ __forceinline__ float bcast_f(float x) {
  return __uint_as_float((unsigned)__builtin_amdgcn_readfirstlane((int)__float_as_uint(x)));
}
__device__ __forceinline__ unsigned bcast_u(unsigned x) {
  return (unsigned)__builtin_amdgcn_readfirstlane((int)x);
}

__global__ __launch_bounds__(256) void gc_init(float* __restrict__ ws) {
  int i = blockIdx.x * 256 + threadIdx.x;
  if (i < ZERO_N) ws[i] = 0.0f;
}

// Phase 1: k0[k][c] = sum over pixels of pos[k,p] * fnorm[c,p]
// 32px x 256c tile, float4 staging (4px x 8ch per thread).
// T14 async-STAGE: next tile's global loads are issued BEFORE the accumulate
// loop so HBM latency/bandwidth hides under the 608-FMA compute phase.
// LDS swizzle col = c ^ row ^ (row>>2): full-rank bank map -> 2-way max on
// both the float4-staged writes and the per-pixel reads.
__global__ __launch_bounds__(256, 4) void gc_phase1(const float* __restrict__ feat,
                                                    const float* __restrict__ gt,
                                                    float* __restrict__ k0) {
  __shared__ float tile[32 * 256];   // [row][c ^ row ^ (row>>2)], 32 KB
  __shared__ float part2[32][33];    // [px][g] sumsq partials, padded
  __shared__ float rnL[32];          // per-pixel 1/||f||
  __shared__ unsigned mskL[32];      // per-pixel 19-bit positive mask

  const int t  = threadIdx.x;
  const int pq = t & 7;              // pixel quad (4 consecutive px)
  const int g  = t >> 3;             // 8-channel group (32 groups)
  const int px = pq << 2;

  float acc[Kn];
#pragma unroll
  for (int k = 0; k < Kn; k++) acc[k] = 0.0f;

  // prologue: prefetch first tile
  int tid = blockIdx.x;
  float4 v4[8];
  {
    const int p0  = tid << 5;
    const int b   = p0 >> 16;
    const int hw0 = p0 & (HW - 1);
    const float* fb = feat + (size_t)b * (Cn * HW) + hw0;
#pragma unroll
    for (int j = 0; j < 8; j++)
      v4[j] = *(const float4*)&fb[(size_t)((g << 3) + j) * HW + px];
  }

  while (tid < P / 32) {
    const int p0  = tid << 5;
    const int b   = p0 >> 16;              // HW == 65536
    const int hw0 = p0 & (HW - 1);

    __syncthreads();   // previous tile fully consumed

    // stage current registers -> LDS (swizzled, conflict-free)
    float ps0 = 0.f, ps1 = 0.f, ps2 = 0.f, ps3 = 0.f;
#pragma unroll
    for (int j = 0; j < 8; j++) {
      const int c = (g << 3) + j;
      ps0 = fmaf(v4[j].x, v4[j].x, ps0);
      ps1 = fmaf(v4[j].y, v4[j].y, ps1);
      ps2 = fmaf(v4[j].z, v4[j].z, ps2);
      ps3 = fmaf(v4[j].w, v4[j].w, ps3);
      // sw(row) = row ^ (row>>2) = (px+i) ^ pq
      tile[((px + 0) << 8) + (c ^ (px + 0) ^ pq)] = v4[j].x;
      tile[((px + 1) << 8) + (c ^ (px + 1) ^ pq)] = v4[j].y;
      tile[((px + 2) << 8) + (c ^ (px + 2) ^ pq)] = v4[j].z;
      tile[((px + 3) << 8) + (c ^ (px + 3) ^ pq)] = v4[j].w;
    }
    part2[px + 0][g] = ps0;
    part2[px + 1][g] = ps1;
    part2[px + 2][g] = ps2;
    part2[px + 3][g] = ps3;

    unsigned msk = 0;
    if (t < 32) {   // gt fetched once per pixel (p == t)
      const float* gb = gt + (size_t)b * (Kn * HW) + hw0 + t;
#pragma unroll
      for (int k = 0; k < Kn; k++)
        msk |= (gb[(size_t)k * HW] == 1.0f) ? (1u << k) : 0u;
    }

    __syncthreads();   // tile + partials visible

    if (t < 32) {
      float fss = 0.0f;
#pragma unroll
      for (int gg = 0; gg < 32; gg++) fss += part2[t][gg];
      rnL[t]  = 1.0f / fmaxf(sqrtf(fss), EPSv);
      mskL[t] = msk;
    }

    __syncthreads();   // rnL/mskL visible

    // T14: issue NEXT tile's global loads now; they complete during the
    // accumulate loop below (v4 already staged to LDS, safe to overwrite).
    const int ntid = tid + gridDim.x;
    if (ntid < P / 32) {
      const int np0  = ntid << 5;
      const int nb   = np0 >> 16;
      const int nhw0 = np0 & (HW - 1);
      const float* nfb = feat + (size_t)nb * (Cn * HW) + nhw0;
#pragma unroll
      for (int j = 0; j < 8; j++)
        v4[j] = *(const float4*)&nfb[(size_t)((g << 3) + j) * HW + px];
    }

    // accumulate: thread t owns channel c=t, loops over the 32 pixels.
    // rn/mk are wave-uniform scalars -> s_cselect + v_fmac.
#pragma unroll 8
    for (int pp = 0; pp < 32; pp++) {
      const float    rn = bcast_f(rnL[pp]);
      const unsigned mk = bcast_u(mskL[pp]);
      const float    fv = tile[(pp << 8) + (t ^ pp ^ (pp >> 2))];
#pragma unroll
      for (int k = 0; k < Kn; k++) {
        const float w = ((mk >> k) & 1u) ? rn : 0.0f;
        acc[k] = fmaf(fv, w, acc[k]);
      }
    }

    tid = ntid;
  }

#pragma unroll
  for (int k = 0; k < Kn; k++) atomicAdd(&k0[k * 256 + t], acc[k]);
}

// Phase 2: row-normalize k0 -> k0n
__global__ __launch_bounds__(256) void gc_phase2(const float* __restrict__ k0,
                                                 float* __restrict__ k0n) {
  const int lane = threadIdx.x & 63;
  const int wv   = threadIdx.x >> 6;
  for (int r = wv; r < Kn; r += 4) {
    float s = 0.0f;
#pragma unroll
    for (int j = 0; j < 4; j++) {
      const float v = k0[r * 256 + (j << 6) + lane];
      s += v * v;
    }
#pragma unroll
    for (int off = 32; off > 0; off >>= 1) s += __shfl_down(s, off);
    s = __shfl(s, 0);
    const float rn = 1.0f / fmaxf(sqrtf(s), EPSv);
#pragma unroll
    for (int j = 0; j < 4; j++) {
      const int c = (j << 6) + lane;
      k0n[r * 256 + c] = k0[r * 256 + c] * rn;
    }
  }
}

// Phase 3 helpers: 4 pixels/thread, float4 loads (16B/lane), weights on the
// scalar pipe (wave-uniform k0n reads). 16-channel buffers keep 16 loads in
// flight during every compute block (ILP latency hiding at 4 waves/CU).
__device__ __forceinline__ void p3_load16(float4 (&dst)[16],
                                          const float* __restrict__ fb, int base) {
#pragma unroll
  for (int j = 0; j < 16; j++)
    dst[j] = *(const float4*)&fb[(size_t)(base + j) * HW];
}

__device__ __forceinline__ void p3_compute16(const float4 (&v)[16], int c0,
                                             const float* __restrict__ k0n,
                                             float (&dot)[Kn][4], float (&ss)[4]) {
#pragma unroll
  for (int j4 = 0; j4 < 16; j4 += 4) {
    const float4 f0 = v[j4 + 0], f1 = v[j4 + 1];
    const float4 f2 = v[j4 + 2], f3 = v[j4 + 3];
    ss[0] = fmaf(f0.x, f0.x, ss[0]); ss[0] = fmaf(f1.x, f1.x, ss[0]);
    ss[0] = fmaf(f2.x, f2.x, ss[0]); ss[0] = fmaf(f3.x, f3.x, ss[0]);
    ss[1] = fmaf(f0.y, f0.y, ss[1]); ss[1] = fmaf(f1.y, f1.y, ss[1]);
    ss[1] = fmaf(f2.y, f2.y, ss[1]); ss[1] = fmaf(f3.y, f3.y, ss[1]);
    ss[2] = fmaf(f0.z, f0.z, ss[2]); ss[2] = fmaf(f1.z, f1.z, ss[2]);
    ss[2] = fmaf(f2.z, f2.z, ss[2]); ss[2] = fmaf(f3.z, f3.z, ss[2]);
    ss[3] = fmaf(f0.w, f0.w, ss[3]); ss[3] = fmaf(f1.w, f1.w, ss[3]);
    ss[3] = fmaf(f2.w, f2.w, ss[3]); ss[3] = fmaf(f3.w, f3.w, ss[3]);
#pragma unroll
    for (int k = 0; k < Kn; k++) {
      const float4 w = *(const float4*)(k0n + k * 256 + c0 + j4);  // uniform
      dot[k][0] = fmaf(f3.x, w.w, fmaf(f2.x, w.z, fmaf(f1.x, w.y, fmaf(f0.x, w.x, dot[k][0]))));
      dot[k][1] = fmaf(f3.y, w.w, fmaf(f2.y, w.z, fmaf(f1.y, w.y, fmaf(f0.y, w.x, dot[k][1]))));
      dot[k][2] = fmaf(f3.z, w.w, fmaf(f2.z, w.z, fmaf(f1.z, w.y, fmaf(f0.z, w.x, dot[k][2]))));
      dot[k][3] = fmaf(f3.w, w.w, fmaf(f2.w, w.z, fmaf(f1.w, w.y, fmaf(f0.w, w.x, dot[k][3]))));
    }
  }
}

// Phase 3: logits + log-softmax + masked loss. 512 blocks x 128 threads,
// thread owns 4 consecutive pixels; all global reads are dwordx4.
__global__ __launch_bounds__(128, 2) void gc_phase3(const float* __restrict__ feat,
                                                    const float* __restrict__ gt,
                                                    const float* __restrict__ k0n,
                                                    float* __restrict__ sums) {
  const int t    = threadIdx.x;
  const int pix0 = blockIdx.x << 9;          // 512 px per block
  const int b    = pix0 >> 16;
  const int hw   = (pix0 & (HW - 1)) + (t << 2);
  const float* fb = feat + (size_t)b * (Cn * HW) + hw;

  float dot[Kn][4];
#pragma unroll
  for (int k = 0; k < Kn; k++)
#pragma unroll
    for (int i = 0; i < 4; i++) dot[k][i] = 0.0f;
  float ss[4] = {0.f, 0.f, 0.f, 0.f};

  float4 va[16], vb[16];
  p3_load16(va, fb, 0);
  for (int c0 = 0; c0 < Cn; c0 += 32) {
    p3_load16(vb, fb, c0 + 16);                 // prefetch odd half
    p3_compute16(va, c0, k0n, dot, ss);         // consume even half
    if (c0 + 32 < Cn) p3_load16(va, fb, c0 + 32);
    p3_compute16(vb, c0 + 16, k0n, dot, ss);    // consume odd half
  }

  const float* gb = gt + (size_t)b * (Kn * HW) + hw;
  float4 gv[Kn];
#pragma unroll
  for (int k = 0; k < Kn; k++) gv[k] = *(const float4*)&gb[(size_t)k * HW];

  float lsum = 0.0f, npos = 0.0f;
#pragma unroll
  for (int i = 0; i < 4; i++) {
    const float sc = 1.0f / (fmaxf(sqrtf(ss[i]), EPSv) * TAUv);
    float mx = -1e30f;
    float d[Kn];
#pragma unroll
    for (int k = 0; k < Kn; k++) { d[k] = dot[k][i] * sc; mx = fmaxf(mx, d[k]); }
    float se = 0.0f;
#pragma unroll
    for (int k = 0; k < Kn; k++) se += __expf(d[k] - mx);
    const float lse = __logf(se) + mx;
#pragma unroll
    for (int k = 0; k < Kn; k++) {
      const float gvi = (i == 0) ? gv[k].x : (i == 1) ? gv[k].y : (i == 2) ? gv[k].z : gv[k].w;
      if (gvi == 1.0f) { lsum += lse - d[k]; npos += 1.0f; }
    }
  }

#pragma unroll
  for (int off = 32; off > 0; off >>= 1) {
    lsum += __shfl_down(lsum, off);
    npos += __shfl_down(npos, off);
  }
  if ((t & 63) == 0) {
    atomicAdd(&sums[0], lsum);
    atomicAdd(&sums[1], npos);
  }
}

__global__ void gc_finalize(const float* __restrict__ sums, float* __restrict__ out) {
  if (threadIdx.x == 0 && blockIdx.x == 0)
    out[0] = sums[0] / sums[1];
}

extern "C" void kernel_launch(void* const* d_in, const int* in_sizes, int n_in,
                              void* d_out, int out_size, void* d_ws, size_t ws_size,
                              hipStream_t stream) {
  const float* feat = (const float*)d_in[0];
  const float* gt   = (const float*)d_in[1];
  float* ws  = (float*)d_ws;
  float* out = (float*)d_out;

  float* k0   = ws + K0_OFF;
  float* k0n  = ws + K0N_OFF;
  float* sums = ws + SUMS_OFF;

  gc_init<<<dim3((ZERO_N + 255) / 256), dim3(256), 0, stream>>>(ws);
  gc_phase1<<<dim3(P1_GRID), dim3(256), 0, stream>>>(feat, gt, k0);
  gc_phase2<<<dim3(1), dim3(256), 0, stream>>>(k0, k0n);
  gc_phase3<<<dim3(P3_GRID), dim3(128), 0, stream>>>(feat, gt, k0n, sums);
  gc_finalize<<<dim3(1), dim3(64), 0, stream>>>(sums, out);
}

// Round 5
// 555.894 us; speedup vs baseline: 1.1368x; 1.1368x over previous
//
#include <hip/hip_runtime.h>
#include <math.h>

namespace {
constexpr int Cn = 256;
constexpr int Kn = 19;
constexpr int HW = 256 * 256;          // 65536
constexpr int P  = 4 * HW;             // 262144 pixels
constexpr float TAUv = 0.07f;
constexpr float EPSv = 1e-12f;

// workspace layout (floats)
constexpr int K0_OFF   = 0;            // [19][256] prototype accumulators
constexpr int K0N_OFF  = 4864;         // [19][256] normalized prototypes
constexpr int SUMS_OFF = 9728;         // {loss_sum, num_pos}
constexpr int ZERO_N   = 9730;
constexpr int P1_GRID  = 1024;
constexpr int P3_GRID  = P / 512;      // 512 blocks, 4 px/thread, 128 thr
}

__global__ __launch_bounds__(256) void gc_init(float* __restrict__ ws) {
  int i = blockIdx.x * 256 + threadIdx.x;
  if (i < ZERO_N) ws[i] = 0.0f;
}

// Phase 1: k0[k][c] = sum over pixels of pos[k,p] * fnorm[c,p]
// 32px x 256c tile, float4 staging (4px x 8ch per thread), T14 prefetch.
// Weight path is now ALL-VALU: per pixel read {rn, mask} as one float2
// (uniform ds_read_b64 broadcast, no readfirstlane), fvn = fv*rn once, and
// per k: acc += fvn * (float)((mk>>k)&1)  -> v_bfe + v_cvt + v_fmac.
// This removes the 57-SALU-per-pixel select chain that serialized all 16
// waves/CU on the shared scalar unit (rounds 1-4 plateau at ~190-210 us).
__global__ __launch_bounds__(256, 4) void gc_phase1(const float* __restrict__ feat,
                                                    const float* __restrict__ gt,
                                                    float* __restrict__ k0) {
  __shared__ float tile[32 * 256];   // [row][c ^ row ^ (row>>2)], 32 KB
  __shared__ float part2[32][33];    // [px][g] sumsq partials, padded
  __shared__ float2 rmL[32];         // per-pixel {1/||f||, asfloat(mask)}

  const int t  = threadIdx.x;
  const int pq = t & 7;              // pixel quad (4 consecutive px)
  const int g  = t >> 3;             // 8-channel group (32 groups)
  const int px = pq << 2;

  float acc[Kn];
#pragma unroll
  for (int k = 0; k < Kn; k++) acc[k] = 0.0f;

  // prologue: prefetch first tile
  int tid = blockIdx.x;
  float4 v4[8];
  {
    const int p0  = tid << 5;
    const int b   = p0 >> 16;
    const int hw0 = p0 & (HW - 1);
    const float* fb = feat + (size_t)b * (Cn * HW) + hw0;
#pragma unroll
    for (int j = 0; j < 8; j++)
      v4[j] = *(const float4*)&fb[(size_t)((g << 3) + j) * HW + px];
  }

  while (tid < P / 32) {
    const int p0  = tid << 5;
    const int b   = p0 >> 16;              // HW == 65536
    const int hw0 = p0 & (HW - 1);

    __syncthreads();   // previous tile fully consumed

    // stage current registers -> LDS (swizzled, conflict-free)
    float ps0 = 0.f, ps1 = 0.f, ps2 = 0.f, ps3 = 0.f;
#pragma unroll
    for (int j = 0; j < 8; j++) {
      const int c = (g << 3) + j;
      ps0 = fmaf(v4[j].x, v4[j].x, ps0);
      ps1 = fmaf(v4[j].y, v4[j].y, ps1);
      ps2 = fmaf(v4[j].z, v4[j].z, ps2);
      ps3 = fmaf(v4[j].w, v4[j].w, ps3);
      // sw(row) = row ^ (row>>2) = (px+i) ^ pq
      tile[((px + 0) << 8) + (c ^ (px + 0) ^ pq)] = v4[j].x;
      tile[((px + 1) << 8) + (c ^ (px + 1) ^ pq)] = v4[j].y;
      tile[((px + 2) << 8) + (c ^ (px + 2) ^ pq)] = v4[j].z;
      tile[((px + 3) << 8) + (c ^ (px + 3) ^ pq)] = v4[j].w;
    }
    part2[px + 0][g] = ps0;
    part2[px + 1][g] = ps1;
    part2[px + 2][g] = ps2;
    part2[px + 3][g] = ps3;

    unsigned msk = 0;
    if (t < 32) {   // gt fetched once per pixel (p == t)
      const float* gb = gt + (size_t)b * (Kn * HW) + hw0 + t;
#pragma unroll
      for (int k = 0; k < Kn; k++)
        msk |= (gb[(size_t)k * HW] == 1.0f) ? (1u << k) : 0u;
    }

    __syncthreads();   // tile + partials visible

    if (t < 32) {
      float fss = 0.0f;
#pragma unroll
      for (int gg = 0; gg < 32; gg++) fss += part2[t][gg];
      rmL[t] = make_float2(1.0f / fmaxf(sqrtf(fss), EPSv),
                           __uint_as_float(msk));
    }

    __syncthreads();   // rmL visible

    // T14: issue NEXT tile's global loads now; they complete during the
    // accumulate loop below (v4 already staged to LDS, safe to overwrite).
    const int ntid = tid + gridDim.x;
    if (ntid < P / 32) {
      const int np0  = ntid << 5;
      const int nb   = np0 >> 16;
      const int nhw0 = np0 & (HW - 1);
      const float* nfb = feat + (size_t)nb * (Cn * HW) + nhw0;
#pragma unroll
      for (int j = 0; j < 8; j++)
        v4[j] = *(const float4*)&nfb[(size_t)((g << 3) + j) * HW + px];
    }

    // accumulate: thread t owns channel c=t, loops over the 32 pixels.
    // Pure VALU: no readfirstlane, no scalar selects, no SGPR weight path.
#pragma unroll 4
    for (int pp = 0; pp < 32; pp++) {
      const float2   rm = rmL[pp];                         // b64 broadcast
      const float    fv = tile[(pp << 8) + (t ^ pp ^ (pp >> 2))];
      const float    fvn = fv * rm.x;
      const unsigned mk = __float_as_uint(rm.y);
#pragma unroll
      for (int k = 0; k < Kn; k++) {
        const float bf = (float)((mk >> k) & 1u);          // v_bfe + v_cvt
        acc[k] = fmaf(fvn, bf, acc[k]);                    // v_fmac
      }
    }

    tid = ntid;
  }

#pragma unroll
  for (int k = 0; k < Kn; k++) atomicAdd(&k0[k * 256 + t], acc[k]);
}

// Phase 2: row-normalize k0 -> k0n
__global__ __launch_bounds__(256) void gc_phase2(const float* __restrict__ k0,
                                                 float* __restrict__ k0n) {
  const int lane = threadIdx.x & 63;
  const int wv   = threadIdx.x >> 6;
  for (int r = wv; r < Kn; r += 4) {
    float s = 0.0f;
#pragma unroll
    for (int j = 0; j < 4; j++) {
      const float v = k0[r * 256 + (j << 6) + lane];
      s += v * v;
    }
#pragma unroll
    for (int off = 32; off > 0; off >>= 1) s += __shfl_down(s, off);
    s = __shfl(s, 0);
    const float rn = 1.0f / fmaxf(sqrtf(s), EPSv);
#pragma unroll
    for (int j = 0; j < 4; j++) {
      const int c = (j << 6) + lane;
      k0n[r * 256 + c] = k0[r * 256 + c] * rn;
    }
  }
}

// Phase 3 helpers: 4 pixels/thread, float4 loads (16B/lane), weights on the
// scalar pipe (wave-uniform k0n reads -> s_load_dwordx4). 8-entry buffers
// (the 16-entry variant in round 4 hit the VGPR cliff and regressed).
__device__ __forceinline__ void p3_load4(float4 (&dst)[8],
                                         const float* __restrict__ fb, int base) {
#pragma unroll
  for (int j = 0; j < 8; j++)
    dst[j] = *(const float4*)&fb[(size_t)(base + j) * HW];
}

__device__ __forceinline__ void p3_compute4(const float4 (&v)[8], int c0,
                                            const float* __restrict__ k0n,
                                            float (&dot)[Kn][4], float (&ss)[4]) {
#pragma unroll
  for (int j4 = 0; j4 < 8; j4 += 4) {
    const float4 f0 = v[j4 + 0], f1 = v[j4 + 1];
    const float4 f2 = v[j4 + 2], f3 = v[j4 + 3];
    ss[0] = fmaf(f0.x, f0.x, ss[0]); ss[0] = fmaf(f1.x, f1.x, ss[0]);
    ss[0] = fmaf(f2.x, f2.x, ss[0]); ss[0] = fmaf(f3.x, f3.x, ss[0]);
    ss[1] = fmaf(f0.y, f0.y, ss[1]); ss[1] = fmaf(f1.y, f1.y, ss[1]);
    ss[1] = fmaf(f2.y, f2.y, ss[1]); ss[1] = fmaf(f3.y, f3.y, ss[1]);
    ss[2] = fmaf(f0.z, f0.z, ss[2]); ss[2] = fmaf(f1.z, f1.z, ss[2]);
    ss[2] = fmaf(f2.z, f2.z, ss[2]); ss[2] = fmaf(f3.z, f3.z, ss[2]);
    ss[3] = fmaf(f0.w, f0.w, ss[3]); ss[3] = fmaf(f1.w, f1.w, ss[3]);
    ss[3] = fmaf(f2.w, f2.w, ss[3]); ss[3] = fmaf(f3.w, f3.w, ss[3]);
#pragma unroll
    for (int k = 0; k < Kn; k++) {
      const float4 w = *(const float4*)(k0n + k * 256 + c0 + j4);  // uniform
      dot[k][0] = fmaf(f3.x, w.w, fmaf(f2.x, w.z, fmaf(f1.x, w.y, fmaf(f0.x, w.x, dot[k][0]))));
      dot[k][1] = fmaf(f3.y, w.w, fmaf(f2.y, w.z, fmaf(f1.y, w.y, fmaf(f0.y, w.x, dot[k][1]))));
      dot[k][2] = fmaf(f3.z, w.w, fmaf(f2.z, w.z, fmaf(f1.z, w.y, fmaf(f0.z, w.x, dot[k][2]))));
      dot[k][3] = fmaf(f3.w, w.w, fmaf(f2.w, w.z, fmaf(f1.w, w.y, fmaf(f0.w, w.x, dot[k][3]))));
    }
  }
}

// Phase 3: logits + log-softmax + masked loss. 512 blocks x 128 threads,
// thread owns 4 consecutive pixels; all global reads are dwordx4.
__global__ __launch_bounds__(128, 2) void gc_phase3(const float* __restrict__ feat,
                                                    const float* __restrict__ gt,
                                                    const float* __restrict__ k0n,
                                                    float* __restrict__ sums) {
  const int t    = threadIdx.x;
  const int pix0 = blockIdx.x << 9;          // 512 px per block
  const int b    = pix0 >> 16;
  const int hw   = (pix0 & (HW - 1)) + (t << 2);
  const float* fb = feat + (size_t)b * (Cn * HW) + hw;

  float dot[Kn][4];
#pragma unroll
  for (int k = 0; k < Kn; k++)
#pragma unroll
    for (int i = 0; i < 4; i++) dot[k][i] = 0.0f;
  float ss[4] = {0.f, 0.f, 0.f, 0.f};

  float4 va[8], vb[8];
  p3_load4(va, fb, 0);
  for (int c0 = 0; c0 < Cn; c0 += 16) {
    p3_load4(vb, fb, c0 + 8);                  // prefetch odd chunk
    p3_compute4(va, c0, k0n, dot, ss);         // consume even chunk
    if (c0 + 16 < Cn) p3_load4(va, fb, c0 + 16);
    p3_compute4(vb, c0 + 8, k0n, dot, ss);     // consume odd chunk
  }

  const float* gb = gt + (size_t)b * (Kn * HW) + hw;
  float4 gv[Kn];
#pragma unroll
  for (int k = 0; k < Kn; k++) gv[k] = *(const float4*)&gb[(size_t)k * HW];

  float lsum = 0.0f, npos = 0.0f;
#pragma unroll
  for (int i = 0; i < 4; i++) {
    const float sc = 1.0f / (fmaxf(sqrtf(ss[i]), EPSv) * TAUv);
    float mx = -1e30f;
    float d[Kn];
#pragma unroll
    for (int k = 0; k < Kn; k++) { d[k] = dot[k][i] * sc; mx = fmaxf(mx, d[k]); }
    float se = 0.0f;
#pragma unroll
    for (int k = 0; k < Kn; k++) se += __expf(d[k] - mx);
    const float lse = __logf(se) + mx;
#pragma unroll
    for (int k = 0; k < Kn; k++) {
      const float gvi = (i == 0) ? gv[k].x : (i == 1) ? gv[k].y : (i == 2) ? gv[k].z : gv[k].w;
      if (gvi == 1.0f) { lsum += lse - d[k]; npos += 1.0f; }
    }
  }

#pragma unroll
  for (int off = 32; off > 0; off >>= 1) {
    lsum += __shfl_down(lsum, off);
    npos += __shfl_down(npos, off);
  }
  if ((t & 63) == 0) {
    atomicAdd(&sums[0], lsum);
    atomicAdd(&sums[1], npos);
  }
}

__global__ void gc_finalize(const float* __restrict__ sums, float* __restrict__ out) {
  if (threadIdx.x == 0 && blockIdx.x == 0)
    out[0] = sums[0] / sums[1];
}

extern "C" void kernel_launch(void* const* d_in, const int* in_sizes, int n_in,
                              void* d_out, int out_size, void* d_ws, size_t ws_size,
                              hipStream_t stream) {
  const float* feat = (const float*)d_in[0];
  const float* gt   = (const float*)d_in[1];
  float* ws  = (float*)d_ws;
  float* out = (float*)d_out;

  float* k0   = ws + K0_OFF;
  float* k0n  = ws + K0N_OFF;
  float* sums = ws + SUMS_OFF;

  gc_init<<<dim3((ZERO_N + 255) / 256), dim3(256), 0, stream>>>(ws);
  gc_phase1<<<dim3(P1_GRID), dim3(256), 0, stream>>>(feat, gt, k0);
  gc_phase2<<<dim3(1), dim3(256), 0, stream>>>(k0, k0n);
  gc_phase3<<<dim3(P3_GRID), dim3(128), 0, stream>>>(feat, gt, k0n, sums);
  gc_finalize<<<dim3(1), dim3(64), 0, stream>>>(sums, out);
}

// Round 6
// 538.955 us; speedup vs baseline: 1.1725x; 1.0314x over previous
//
#include <hip/hip_runtime.h>
#include <math.h>

namespace {
constexpr int Cn = 256;
constexpr int Kn = 19;
constexpr int HW = 256 * 256;          // 65536
constexpr int P  = 4 * HW;             // 262144 pixels
constexpr float TAUv = 0.07f;
constexpr float EPSv = 1e-12f;

constexpr int TPX = 16;                // phase1 tile pixels
constexpr int NT  = P / TPX;           // 16384 tiles

// workspace layout (floats)
constexpr int K0_OFF   = 0;            // [19][256] prototype accumulators
constexpr int K0N_OFF  = 4864;         // [19][256] normalized prototypes
constexpr int SUMS_OFF = 9728;         // {loss_sum, num_pos}
constexpr int ZERO_N   = 9730;
constexpr int P1_GRID  = 1024;
constexpr int P3_GRID  = P / 256;      // 1024 blocks, 2 px/thread, 128 thr
}

__global__ __launch_bounds__(256) void gc_init(float* __restrict__ ws) {
  int i = blockIdx.x * 256 + threadIdx.x;
  if (i < ZERO_N) ws[i] = 0.0f;
}

// ---------------------------------------------------------------------------
// Phase 1: k0[k][c] = sum over pixels of pos[k,p] * fnorm[c,p]
// Round-5 lesson: 3 barriers/tile + a t<32 serial reduce convoyed all waves;
// pipes ran sequentially (measured round time == sum of pipe times).
// New structure: 16-px tiles, DOUBLE-BUFFERED (one barrier per tile);
// per-pixel sumsq via in-wave shfl_xor butterflies + 4 per-wave partials;
// rn computed redundantly per-thread (no serial section, no second barrier);
// next tile's feat+gt loads issued right after the barrier so memory is in
// flight during the whole accumulate.
// ---------------------------------------------------------------------------
__device__ __forceinline__ void p1_load(float4 (&v4)[4], float (&gtv)[Kn],
                                        const float* __restrict__ feat,
                                        const float* __restrict__ gt,
                                        int tid, int t, int g, int pq) {
  const int p0  = tid << 4;            // * TPX
  const int b   = p0 >> 16;            // HW == 65536
  const int hw0 = p0 & (HW - 1);
  const float* fb = feat + (size_t)b * (Cn * HW) + hw0;
#pragma unroll
  for (int j = 0; j < 4; j++)
    v4[j] = *(const float4*)&fb[(size_t)((g << 2) + j) * HW + (pq << 2)];
  if (t < TPX) {
    const float* gb = gt + (size_t)b * (Kn * HW) + hw0 + t;
#pragma unroll
    for (int k = 0; k < Kn; k++) gtv[k] = gb[(size_t)k * HW];
  }
}

__global__ __launch_bounds__(256, 4) void gc_phase1(const float* __restrict__ feat,
                                                    const float* __restrict__ gt,
                                                    float* __restrict__ k0) {
  __shared__ float tile[2][TPX * 256];   // [buf][px][c ^ (px>>2)], 32 KB
  __shared__ float swpf[2][TPX][4];      // [buf][px][wave] sumsq partials
  __shared__ unsigned mskI[2][TPX];      // [buf][px] 19-bit positive mask

  const int t    = threadIdx.x;
  const int pq   = t & 3;                // pixel quad (4 consecutive px)
  const int g    = t >> 2;               // 4-channel group (64 groups)
  const int lane = t & 63;
  const int wv   = t >> 6;

  float acc[Kn];
#pragma unroll
  for (int k = 0; k < Kn; k++) acc[k] = 0.0f;

  int tid = blockIdx.x;
  float4 v4[4];
  float  gtv[Kn];
  p1_load(v4, gtv, feat, gt, tid, t, g, pq);   // prologue prefetch

  int cur = 0;
  while (tid < NT) {
    // ---- stage current tile into buf[cur] (pre-barrier) ----
    float ps0 = 0.f, ps1 = 0.f, ps2 = 0.f, ps3 = 0.f;
    const int px = pq << 2;
#pragma unroll
    for (int j = 0; j < 4; j++) {
      const int c = (g << 2) + j;
      ps0 = fmaf(v4[j].x, v4[j].x, ps0);
      ps1 = fmaf(v4[j].y, v4[j].y, ps1);
      ps2 = fmaf(v4[j].z, v4[j].z, ps2);
      ps3 = fmaf(v4[j].w, v4[j].w, ps3);
      // swizzle sw(px) = px>>2 = pq -> 2-way max on writes and reads
      tile[cur][((px + 0) << 8) + (c ^ pq)] = v4[j].x;
      tile[cur][((px + 1) << 8) + (c ^ pq)] = v4[j].y;
      tile[cur][((px + 2) << 8) + (c ^ pq)] = v4[j].z;
      tile[cur][((px + 3) << 8) + (c ^ pq)] = v4[j].w;
    }
    // in-wave butterfly over the 16 lanes sharing pq (lane bits 2..5)
#pragma unroll
    for (int m = 4; m <= 32; m <<= 1) {
      ps0 += __shfl_xor(ps0, m);
      ps1 += __shfl_xor(ps1, m);
      ps2 += __shfl_xor(ps2, m);
      ps3 += __shfl_xor(ps3, m);
    }
    if (lane < 4) {                      // lane == pq: per-wave partials
      swpf[cur][(lane << 2) + 0][wv] = ps0;
      swpf[cur][(lane << 2) + 1][wv] = ps1;
      swpf[cur][(lane << 2) + 2][wv] = ps2;
      swpf[cur][(lane << 2) + 3][wv] = ps3;
    }
    if (t < TPX) {
      unsigned m = 0;
#pragma unroll
      for (int k = 0; k < Kn; k++)
        m |= (gtv[k] == 1.0f) ? (1u << k) : 0u;
      mskI[cur][t] = m;
    }

    __syncthreads();   // the ONLY barrier: stage visible, prev acc done

    // ---- prefetch next tile (flies during accumulate) ----
    const int ntid = tid + P1_GRID;
    if (ntid < NT) p1_load(v4, gtv, feat, gt, ntid, t, g, pq);

    // ---- accumulate: thread t owns channel c=t over 16 pixels ----
#pragma unroll 4
    for (int pp = 0; pp < TPX; pp++) {
      const float4 sp = *(const float4*)&swpf[cur][pp][0];   // uniform b128
      const float fss = ((sp.x + sp.y) + sp.z) + sp.w;
      const float rn  = 1.0f / fmaxf(sqrtf(fss), EPSv);      // redundant/thread
      const unsigned mk = mskI[cur][pp];                     // uniform b32
      const float fv  = tile[cur][(pp << 8) + (t ^ (pp >> 2))];
      const float fvn = fv * rn;
#pragma unroll
      for (int k = 0; k < Kn; k++) {
        const float bf = (float)((mk >> k) & 1u);            // v_bfe + v_cvt
        acc[k] = fmaf(fvn, bf, acc[k]);                      // v_fmac
      }
    }

    tid = ntid;
    cur ^= 1;
  }

#pragma unroll
  for (int k = 0; k < Kn; k++) atomicAdd(&k0[k * 256 + t], acc[k]);
}

// Phase 2: row-normalize k0 -> k0n
__global__ __launch_bounds__(256) void gc_phase2(const float* __restrict__ k0,
                                                 float* __restrict__ k0n) {
  const int lane = threadIdx.x & 63;
  const int wv   = threadIdx.x >> 6;
  for (int r = wv; r < Kn; r += 4) {
    float s = 0.0f;
#pragma unroll
    for (int j = 0; j < 4; j++) {
      const float v = k0[r * 256 + (j << 6) + lane];
      s += v * v;
    }
#pragma unroll
    for (int off = 32; off > 0; off >>= 1) s += __shfl_down(s, off);
    s = __shfl(s, 0);
    const float rn = 1.0f / fmaxf(sqrtf(s), EPSv);
#pragma unroll
    for (int j = 0; j < 4; j++) {
      const int c = (j << 6) + lane;
      k0n[r * 256 + c] = k0[r * 256 + c] * rn;
    }
  }
}

// ---------------------------------------------------------------------------
// Phase 3: logits + log-softmax + masked loss.
// Round-5 lesson: 512 blocks x 128 thr = 1 wave/SIMD -> zero TLP, every
// stall exposed. Now 2 px/thread, 1024 blocks x 128 thr = 2 waves/SIMD.
// float2 loads (8 B/lane, 512 B/instr coalesced); k0n on the scalar pipe.
// ---------------------------------------------------------------------------
__device__ __forceinline__ void p3_load8(float2 (&dst)[8],
                                         const float* __restrict__ fb, int base) {
#pragma unroll
  for (int j = 0; j < 8; j++)
    dst[j] = *(const float2*)&fb[(size_t)(base + j) * HW];
}

__device__ __forceinline__ void p3_comp8(const float2 (&v)[8], int c0,
                                         const float* __restrict__ k0n,
                                         float (&dot)[Kn][2], float (&ss)[2]) {
#pragma unroll
  for (int j4 = 0; j4 < 8; j4 += 4) {
    const float2 f0 = v[j4 + 0], f1 = v[j4 + 1];
    const float2 f2 = v[j4 + 2], f3 = v[j4 + 3];
    ss[0] = fmaf(f0.x, f0.x, ss[0]); ss[0] = fmaf(f1.x, f1.x, ss[0]);
    ss[0] = fmaf(f2.x, f2.x, ss[0]); ss[0] = fmaf(f3.x, f3.x, ss[0]);
    ss[1] = fmaf(f0.y, f0.y, ss[1]); ss[1] = fmaf(f1.y, f1.y, ss[1]);
    ss[1] = fmaf(f2.y, f2.y, ss[1]); ss[1] = fmaf(f3.y, f3.y, ss[1]);
#pragma unroll
    for (int k = 0; k < Kn; k++) {
      const float4 w = *(const float4*)(k0n + k * 256 + c0 + j4);  // uniform
      dot[k][0] = fmaf(f3.x, w.w, fmaf(f2.x, w.z, fmaf(f1.x, w.y, fmaf(f0.x, w.x, dot[k][0]))));
      dot[k][1] = fmaf(f3.y, w.w, fmaf(f2.y, w.z, fmaf(f1.y, w.y, fmaf(f0.y, w.x, dot[k][1]))));
    }
  }
}

__global__ __launch_bounds__(128, 2) void gc_phase3(const float* __restrict__ feat,
                                                    const float* __restrict__ gt,
                                                    const float* __restrict__ k0n,
                                                    float* __restrict__ sums) {
  const int t    = threadIdx.x;
  const int pix0 = blockIdx.x << 8;          // 256 px per block
  const int b    = pix0 >> 16;
  const int hw   = (pix0 & (HW - 1)) + (t << 1);
  const float* fb = feat + (size_t)b * (Cn * HW) + hw;

  float dot[Kn][2];
#pragma unroll
  for (int k = 0; k < Kn; k++) { dot[k][0] = 0.0f; dot[k][1] = 0.0f; }
  float ss[2] = {0.f, 0.f};

  float2 va[8], vb[8];
  p3_load8(va, fb, 0);
  for (int c0 = 0; c0 < Cn; c0 += 16) {
    p3_load8(vb, fb, c0 + 8);                  // prefetch odd chunk
    p3_comp8(va, c0, k0n, dot, ss);            // consume even chunk
    if (c0 + 16 < Cn) p3_load8(va, fb, c0 + 16);
    p3_comp8(vb, c0 + 8, k0n, dot, ss);        // consume odd chunk
  }

  const float* gb = gt + (size_t)b * (Kn * HW) + hw;
  float2 gv[Kn];
#pragma unroll
  for (int k = 0; k < Kn; k++) gv[k] = *(const float2*)&gb[(size_t)k * HW];

  float lsum = 0.0f, npos = 0.0f;
#pragma unroll
  for (int i = 0; i < 2; i++) {
    const float sc = 1.0f / (fmaxf(sqrtf(ss[i]), EPSv) * TAUv);
    float mx = -1e30f;
    float d[Kn];
#pragma unroll
    for (int k = 0; k < Kn; k++) { d[k] = dot[k][i] * sc; mx = fmaxf(mx, d[k]); }
    float se = 0.0f;
#pragma unroll
    for (int k = 0; k < Kn; k++) se += __expf(d[k] - mx);
    const float lse = __logf(se) + mx;
#pragma unroll
    for (int k = 0; k < Kn; k++) {
      const float gvi = (i == 0) ? gv[k].x : gv[k].y;
      if (gvi == 1.0f) { lsum += lse - d[k]; npos += 1.0f; }
    }
  }

#pragma unroll
  for (int off = 32; off > 0; off >>= 1) {
    lsum += __shfl_down(lsum, off);
    npos += __shfl_down(npos, off);
  }
  if ((t & 63) == 0) {
    atomicAdd(&sums[0], lsum);
    atomicAdd(&sums[1], npos);
  }
}

__global__ void gc_finalize(const float* __restrict__ sums, float* __restrict__ out) {
  if (threadIdx.x == 0 && blockIdx.x == 0)
    out[0] = sums[0] / sums[1];
}

extern "C" void kernel_launch(void* const* d_in, const int* in_sizes, int n_in,
                              void* d_out, int out_size, void* d_ws, size_t ws_size,
                              hipStream_t stream) {
  const float* feat = (const float*)d_in[0];
  const float* gt   = (const float*)d_in[1];
  float* ws  = (float*)d_ws;
  float* out = (float*)d_out;

  float* k0   = ws + K0_OFF;
  float* k0n  = ws + K0N_OFF;
  float* sums = ws + SUMS_OFF;

  gc_init<<<dim3((ZERO_N + 255) / 256), dim3(256), 0, stream>>>(ws);
  gc_phase1<<<dim3(P1_GRID), dim3(256), 0, stream>>>(feat, gt, k0);
  gc_phase2<<<dim3(1), dim3(256), 0, stream>>>(k0, k0n);
  gc_phase3<<<dim3(P3_GRID), dim3(128), 0, stream>>>(feat, gt, k0n, sums);
  gc_finalize<<<dim3(1), dim3(64), 0, stream>>>(sums, out);
}